// Round 2
// baseline (27147.818 us; speedup 1.0000x reference)
//
#include <hip/hip_runtime.h>
#include <cstddef>

#define B_   4096
#define L_   64
#define T_   256
#define H_   8
#define HD_  32
#define NL_  4
#define DFF_ 1024
#define DIN_ 6

// ---------------- helpers ----------------
__device__ __forceinline__ float wred_sum(float v) {
#pragma unroll
  for (int off = 32; off >= 1; off >>= 1) v += __shfl_xor(v, off, 64);
  return v;
}
__device__ __forceinline__ float wred_max(float v) {
#pragma unroll
  for (int off = 32; off >= 1; off >>= 1) v = fmaxf(v, __shfl_xor(v, off, 64));
  return v;
}

// ---------------- input normalization ----------------
// one block per batch element, 64 threads (one per link)
__global__ __launch_bounds__(64) void normalize_k(const float* __restrict__ xs,
                                                  float* __restrict__ xn) {
  const int b = blockIdx.x;
  const int l = threadIdx.x;
  const float* x = xs + ((size_t)b * L_ + l) * DIN_;
  const float x0 = x[0], x1 = x[1], x2 = x[2], x3 = x[3], x4 = x[4], x5 = x[5];
  const float prop = fmaxf(x0, 0.f), tx = fmaxf(x1, 0.f);
  const float sp = prop + tx;

  __shared__ float sh[64];
  __shared__ float med_sh;
  sh[l] = sp;
  __syncthreads();
  int rk = 0;
#pragma unroll 8
  for (int j = 0; j < 64; ++j) {
    const float vj = sh[j];
    rk += (vj < sp) || (vj == sp && j < l);
  }
  if (rk == 31) med_sh = sp;  // stable-sort position 31 == jnp.sort(...)[31]
  __syncthreads();
  const float t_ref = fmaxf(med_sh, 1e-6f);

  float f[5];
  f[0] = prop / t_ref;
  f[1] = tx / t_ref;
  f[2] = x2;
  f[3] = log1pf(fmaxf(x3, 0.f));
  f[4] = log1pf(fmaxf(x4, 0.f) / t_ref);
  const float f5 = log1pf(fmaxf(x5, 0.f));

  float* dst = xn + ((size_t)b * L_ + l) * DIN_;
#pragma unroll
  for (int i = 0; i < 5; ++i) {
    float v = f[i];
    float m = wred_sum(v) * (1.f / 64.f);
    float d = v - m;
    float sd = sqrtf(wred_sum(d * d) * (1.f / 64.f)) + 1e-9f;
    const float lo = m - 3.f * sd, hi = m + 3.f * sd;
    const float cv = fminf(fmaxf(v, lo), hi);
    const float m2 = wred_sum(cv) * (1.f / 64.f);
    const float d2 = cv - m2;
    const float sd2 = sqrtf(wred_sum(d2 * d2) * (1.f / 64.f)) + 1e-9f;
    dst[i] = (cv - m2) / sd2;
  }
  dst[5] = f5;
}

// ---------------- positional encoding table ----------------
__global__ void pe_k(float* __restrict__ pe) {
  const int l = blockIdx.x;      // 64
  const int i = threadIdx.x;     // 128
  const float div = expf(-9.210340371976184f * (2.0f * i) / 256.0f);
  const float ang = (float)l * div;
  pe[l * T_ + 2 * i]     = sinf(ang);
  pe[l * T_ + 2 * i + 1] = cosf(ang);
}

// ---------------- generic batched transpose (R x C -> C x R) ----------------
__global__ void transpose_k(const float* __restrict__ src, float* __restrict__ dst,
                            int R, int C) {
  const size_t m = blockIdx.z;
  const int idx = blockIdx.x * 256 + threadIdx.x;
  const int n = R * C;
  if (idx < n) {
    const int r = idx / C, c = idx - r * C;
    dst[m * (size_t)n + (size_t)c * R + r] = src[m * (size_t)n + idx];
  }
}

// ---------------- link MLP stage 1: h = relu(x @ W1[l] + b1[l]) ----------------
__global__ __launch_bounds__(256) void link1_k(const float* __restrict__ xn,
                                               const float* __restrict__ W1,
                                               const float* __restrict__ b1,
                                               float* __restrict__ h) {
  const size_t bl = blockIdx.x;       // local b*L + l (chunk starts at whole b)
  const int l = (int)(bl & (L_ - 1));
  const int t = threadIdx.x;
  const float* x = xn + bl * DIN_;
  float a = b1[l * T_ + t];
#pragma unroll
  for (int d = 0; d < DIN_; ++d)
    a = fmaf(x[d], W1[((size_t)l * DIN_ + d) * T_ + t], a);
  h[bl * T_ + t] = fmaxf(a, 0.f);
}

// ---------------- generic 64-row GEMM, fused epilogues ----------------
// tile: 64 rows x 256 cols per block; 256 threads; thread = 16 rows x 4 cols
// A staged transposed in LDS; W is k-major (K x wn)
// EPI: 0 = +bias, 1 = +bias,relu, 2 = +bias+bias2(pe), 3 = +bias,+resid,LayerNorm
template <int EPI>
__global__ __launch_bounds__(256) void gemm64(
    const float* __restrict__ A, long a_stride, long az,
    const float* __restrict__ Wt, long wz, int K, int wn,
    const float* __restrict__ bias, const float* __restrict__ bias2, long bz,
    const float* __restrict__ resid,
    const float* __restrict__ lng, const float* __restrict__ lnb,
    float* __restrict__ out, long o_stride, long oz) {
  const int tid = threadIdx.x;
  const int tx = tid & 63, ty = tid >> 6;
  const int cfull = blockIdx.y * 256 + tx * 4;
  const size_t b0 = (size_t)blockIdx.x * 64;
  const size_t z = blockIdx.z;

  const float* Ab = A + z * az;
  const float* Wb = Wt + z * wz;

  __shared__ float At[256][68];

  float4 acc[16];
#pragma unroll
  for (int r = 0; r < 16; ++r) acc[r] = make_float4(0.f, 0.f, 0.f, 0.f);

  const int r0 = ty * 16;

  for (int kt = 0; kt < K; kt += 256) {
    __syncthreads();
    {
      const int rr = tid >> 6;
      const int k4 = (tid & 63) * 4;
#pragma unroll
      for (int p = 0; p < 16; ++p) {
        const int r = p * 4 + rr;
        const float4 v = *(const float4*)(Ab + (b0 + r) * a_stride + kt + k4);
        At[k4 + 0][r] = v.x;
        At[k4 + 1][r] = v.y;
        At[k4 + 2][r] = v.z;
        At[k4 + 3][r] = v.w;
      }
    }
    __syncthreads();
    const float* wp = Wb + (size_t)kt * wn + cfull;
#pragma unroll 2
    for (int k = 0; k < 256; ++k) {
      const float4 w = *(const float4*)wp;
      wp += wn;
      const float4* ar = (const float4*)(&At[k][r0]);
      const float4 a0 = ar[0], a1 = ar[1], a2 = ar[2], a3 = ar[3];
      const float av[16] = {a0.x, a0.y, a0.z, a0.w, a1.x, a1.y, a1.z, a1.w,
                            a2.x, a2.y, a2.z, a2.w, a3.x, a3.y, a3.z, a3.w};
#pragma unroll
      for (int r = 0; r < 16; ++r) {
        acc[r].x = fmaf(av[r], w.x, acc[r].x);
        acc[r].y = fmaf(av[r], w.y, acc[r].y);
        acc[r].z = fmaf(av[r], w.z, acc[r].z);
        acc[r].w = fmaf(av[r], w.w, acc[r].w);
      }
    }
  }

  const float4 bb = *(const float4*)(bias + z * bz + cfull);

  if constexpr (EPI == 3) {
    const float4 gv = *(const float4*)(lng + cfull);
    const float4 bv = *(const float4*)(lnb + cfull);
#pragma unroll
    for (int r = 0; r < 16; ++r) {
      const size_t row = b0 + r0 + r;
      const float4 res = *(const float4*)(resid + row * 256 + cfull);
      const float zx = acc[r].x + bb.x + res.x;
      const float zy = acc[r].y + bb.y + res.y;
      const float zz = acc[r].z + bb.z + res.z;
      const float zw = acc[r].w + bb.w + res.w;
      float s1 = zx + zy + zz + zw;
      float s2 = zx * zx + zy * zy + zz * zz + zw * zw;
      s1 = wred_sum(s1);
      s2 = wred_sum(s2);
      const float m = s1 * (1.f / 256.f);
      const float var = s2 * (1.f / 256.f) - m * m;
      const float rs = rsqrtf(var + 1e-5f);
      float4 o;
      o.x = (zx - m) * rs * gv.x + bv.x;
      o.y = (zy - m) * rs * gv.y + bv.y;
      o.z = (zz - m) * rs * gv.z + bv.z;
      o.w = (zw - m) * rs * gv.w + bv.w;
      *(float4*)(out + row * o_stride + z * oz + cfull) = o;
    }
  } else {
    float4 b2v = make_float4(0.f, 0.f, 0.f, 0.f);
    if constexpr (EPI == 2) b2v = *(const float4*)(bias2 + z * bz + cfull);
#pragma unroll
    for (int r = 0; r < 16; ++r) {
      const size_t row = b0 + r0 + r;
      float4 o;
      o.x = acc[r].x + bb.x + b2v.x;
      o.y = acc[r].y + bb.y + b2v.y;
      o.z = acc[r].z + bb.z + b2v.z;
      o.w = acc[r].w + bb.w + b2v.w;
      if constexpr (EPI == 1) {
        o.x = fmaxf(o.x, 0.f);
        o.y = fmaxf(o.y, 0.f);
        o.z = fmaxf(o.z, 0.f);
        o.w = fmaxf(o.w, 0.f);
      }
      *(float4*)(out + row * o_stride + z * oz + cfull) = o;
    }
  }
}

// ---------------- fused attention per (b, h), b local to chunk ----------------
__global__ __launch_bounds__(256) void attn_k(const float* __restrict__ qkv,
                                              float* __restrict__ o) {
  const int b = blockIdx.x;
  const int h = blockIdx.y;
  __shared__ float q[64][33], kk[64][33], vv[64][33], p[64][65];
  const int tid = threadIdx.x;
  const int d = tid & 31, rr = tid >> 5;  // load/PV mapping

#pragma unroll
  for (int pas = 0; pas < 8; ++pas) {
    const int i = pas * 8 + rr;
    const size_t base = ((size_t)b * L_ + i) * (3 * T_) + h * HD_ + d;
    q[i][d] = qkv[base];
    kk[i][d] = qkv[base + T_];
    vv[i][d] = qkv[base + 2 * T_];
  }
  __syncthreads();

  const int j = tid & 63, ig = tid >> 6;
  float s[16];
#pragma unroll
  for (int ii = 0; ii < 16; ++ii) {
    const int i = ig * 16 + ii;
    float a = 0.f;
#pragma unroll
    for (int dd = 0; dd < 32; ++dd) a = fmaf(q[i][dd], kk[j][dd], a);
    s[ii] = a * 0.17677669529663687f;  // 1/sqrt(32)
  }
#pragma unroll
  for (int ii = 0; ii < 16; ++ii) {
    const float m = wred_max(s[ii]);
    const float e = expf(s[ii] - m);
    const float sum = wred_sum(e);
    p[ig * 16 + ii][j] = e / sum;
  }
  __syncthreads();

#pragma unroll
  for (int pas = 0; pas < 8; ++pas) {
    const int i = pas * 8 + rr;
    float a = 0.f;
#pragma unroll
    for (int jj = 0; jj < 64; ++jj) a = fmaf(p[i][jj], vv[jj][d], a);
    o[((size_t)b * L_ + i) * T_ + h * HD_ + d] = a;
  }
}

// ---------------- pooling & head ----------------
__global__ __launch_bounds__(256) void pooled_k(const float* __restrict__ y,
                                                float* __restrict__ pooled) {
  const size_t b = blockIdx.x;
  const int t = threadIdx.x;
  const float* p = y + b * (L_ * T_) + t;
  float s = 0.f;
#pragma unroll
  for (int l = 0; l < L_; ++l) s += p[l * T_];
  pooled[b * T_ + t] = s * (1.f / 64.f);
}

__global__ __launch_bounds__(64) void head2_k(const float* __restrict__ hh,
                                              const float* __restrict__ W2,
                                              const float* __restrict__ b2,
                                              float* __restrict__ out) {
  const size_t b = blockIdx.x;
  const int lane = threadIdx.x;
  const float4 hv = *(const float4*)(hh + b * T_ + lane * 4);
  const float4 wv = *(const float4*)(W2 + lane * 4);
  float s = hv.x * wv.x + hv.y * wv.y + hv.z * wv.z + hv.w * wv.w;
  s = wred_sum(s);
  if (lane == 0) out[b] = s + b2[0];
}

// ---------------- launch ----------------
extern "C" void kernel_launch(void* const* d_in, const int* in_sizes, int n_in,
                              void* d_out, int out_size, void* d_ws, size_t ws_size,
                              hipStream_t stream) {
  const float* link_states = (const float*)d_in[0];
  const float* link_W1 = (const float*)d_in[1];
  const float* link_b1 = (const float*)d_in[2];
  const float* link_W2 = (const float*)d_in[3];
  const float* link_b2 = (const float*)d_in[4];
  const float* Wqkv = (const float*)d_in[5];
  const float* bqkv = (const float*)d_in[6];
  const float* Wo = (const float*)d_in[7];
  const float* bo = (const float*)d_in[8];
  const float* ln1_g = (const float*)d_in[9];
  const float* ln1_b = (const float*)d_in[10];
  const float* Wff1 = (const float*)d_in[11];
  const float* bff1 = (const float*)d_in[12];
  const float* Wff2 = (const float*)d_in[13];
  const float* bff2 = (const float*)d_in[14];
  const float* ln2_g = (const float*)d_in[15];
  const float* ln2_b = (const float*)d_in[16];
  const float* head_W1 = (const float*)d_in[17];
  const float* head_b1 = (const float*)d_in[18];
  const float* head_W2 = (const float*)d_in[19];
  const float* head_b2 = (const float*)d_in[20];

  float* ws = (float*)d_ws;
  size_t off = 0;
  auto alloc = [&](size_t n) {
    float* p = ws + off;
    off += (n + 63) & ~(size_t)63;
    return p;
  };
  // ---- fixed allocations (27.4 MB) ----
  float* WqkvT = alloc((size_t)NL_ * T_ * 3 * T_);        // (NL, 256, 768)
  float* WoT   = alloc((size_t)NL_ * T_ * T_);            // (NL, 256, 256)
  float* Wff1T = alloc((size_t)NL_ * T_ * DFF_);          // (NL, 256, 1024)
  float* Wff2T = alloc((size_t)NL_ * DFF_ * T_);          // (NL, 1024, 256)
  float* pe    = alloc((size_t)L_ * T_);
  float* xn    = alloc((size_t)B_ * L_ * DIN_);
  float* pooled = alloc((size_t)B_ * T_);
  float* hh     = alloc((size_t)B_ * T_);

  // ---- chunked activation buffers, sized from ws_size at runtime ----
  // per-chunk floats: Bc*L*(T + T + DFF) = Bc*98304
  const size_t total_f = ws_size / sizeof(float);
  const size_t avail_f = (total_f > off + 4096) ? (total_f - off - 4096) : 0;
  int NC = 1;
  while (NC < 64 && ((size_t)(B_ / NC)) * 98304ull > avail_f) NC <<= 1;
  const int Bc = B_ / NC;  // >= 64, power of two

  float* y    = alloc((size_t)Bc * L_ * T_);
  float* bufB = alloc((size_t)Bc * L_ * T_);              // h / attn-out
  float* bufA = alloc((size_t)Bc * L_ * DFF_);            // qkv / ff1

  // ---- prep: transposes + pe + normalize (full batch) ----
  transpose_k<<<dim3(768, 1, NL_), 256, 0, stream>>>(Wqkv, WqkvT, 3 * T_, T_);
  transpose_k<<<dim3(256, 1, NL_), 256, 0, stream>>>(Wo, WoT, T_, T_);
  transpose_k<<<dim3(1024, 1, NL_), 256, 0, stream>>>(Wff1, Wff1T, DFF_, T_);
  transpose_k<<<dim3(1024, 1, NL_), 256, 0, stream>>>(Wff2, Wff2T, T_, DFF_);
  pe_k<<<L_, 128, 0, stream>>>(pe);
  normalize_k<<<B_, 64, 0, stream>>>(link_states, xn);

  for (int c = 0; c < NC; ++c) {
    const size_t bs = (size_t)c * Bc;

    // ---- link MLP ----
    link1_k<<<Bc * L_, 256, 0, stream>>>(xn + bs * L_ * DIN_, link_W1, link_b1, bufB);
    // y = h @ W2[l] + b2[l] + pe  (per-l GEMM via blockIdx.z)
    gemm64<2><<<dim3(Bc / 64, 1, L_), 256, 0, stream>>>(
        bufB, L_ * T_, T_, link_W2, (long)T_ * T_, T_, T_,
        link_b2, pe, T_, nullptr, nullptr, nullptr, y, L_ * T_, T_);

    const int M64 = (Bc * L_) / 64;
    for (int l = 0; l < NL_; ++l) {
      // qkv = y @ Wqkv[l]^T + bqkv[l]
      gemm64<0><<<dim3(M64, 3, 1), 256, 0, stream>>>(
          y, T_, 0, WqkvT + (size_t)l * T_ * 3 * T_, 0, T_, 3 * T_,
          bqkv + l * 3 * T_, nullptr, 0, nullptr, nullptr, nullptr, bufA, 3 * T_, 0);
      // attention
      attn_k<<<dim3(Bc, H_, 1), 256, 0, stream>>>(bufA, bufB);
      // y = LN(y + attn_out @ Wo[l]^T + bo[l])
      gemm64<3><<<dim3(M64, 1, 1), 256, 0, stream>>>(
          bufB, T_, 0, WoT + (size_t)l * T_ * T_, 0, T_, T_,
          bo + l * T_, nullptr, 0, y, ln1_g + l * T_, ln1_b + l * T_, y, T_, 0);
      // ff1 = relu(y @ Wff1[l]^T + bff1[l])
      gemm64<1><<<dim3(M64, 4, 1), 256, 0, stream>>>(
          y, T_, 0, Wff1T + (size_t)l * T_ * DFF_, 0, T_, DFF_,
          bff1 + l * DFF_, nullptr, 0, nullptr, nullptr, nullptr, bufA, DFF_, 0);
      // y = LN(y + ff1 @ Wff2[l]^T + bff2[l])
      gemm64<3><<<dim3(M64, 1, 1), 256, 0, stream>>>(
          bufA, DFF_, 0, Wff2T + (size_t)l * DFF_ * T_, 0, DFF_, T_,
          bff2 + l * T_, nullptr, 0, y, ln2_g + l * T_, ln2_b + l * T_, y, T_, 0);
    }

    // ---- pooling (into full-batch pooled buffer) ----
    pooled_k<<<Bc, 256, 0, stream>>>(y, pooled + bs * T_);
  }

  // ---- head (full batch) ----
  gemm64<1><<<dim3(B_ / 64, 1, 1), 256, 0, stream>>>(
      pooled, T_, 0, head_W1, 0, T_, T_,
      head_b1, nullptr, 0, nullptr, nullptr, nullptr, hh, T_, 0);
  head2_k<<<B_, 64, 0, stream>>>(hh, head_W2, head_b2, (float*)d_out);
}

// Round 3
// 8299.511 us; speedup vs baseline: 3.2710x; 3.2710x over previous
//
#include <hip/hip_runtime.h>
#include <cstddef>

#define B_   4096
#define L_   64
#define T_   256
#define H_   8
#define HD_  32
#define NL_  4
#define DFF_ 1024
#define DIN_ 6

typedef unsigned short ushort_t;
typedef __attribute__((ext_vector_type(8))) short bf16x8;
typedef __attribute__((ext_vector_type(4))) float f32x4;

// ---------------- helpers ----------------
__device__ __forceinline__ float wred_sum(float v) {
#pragma unroll
  for (int off = 32; off >= 1; off >>= 1) v += __shfl_xor(v, off, 64);
  return v;
}
__device__ __forceinline__ float wred_max(float v) {
#pragma unroll
  for (int off = 32; off >= 1; off >>= 1) v = fmaxf(v, __shfl_xor(v, off, 64));
  return v;
}
__device__ __forceinline__ ushort_t f2bf(float f) {
  unsigned u = __builtin_bit_cast(unsigned, f);
  u += 0x7fffu + ((u >> 16) & 1u);  // RNE
  return (ushort_t)(u >> 16);
}
__device__ __forceinline__ float bf2f(ushort_t h) {
  unsigned u = ((unsigned)h) << 16;
  return __builtin_bit_cast(float, u);
}
__device__ __forceinline__ void gl16(const ushort_t* g, const ushort_t* l) {
  __builtin_amdgcn_global_load_lds(
      (const __attribute__((address_space(1))) unsigned int*)g,
      (__attribute__((address_space(3))) unsigned int*)l, 16, 0, 0);
}

// ---------------- input normalization (fp32, unchanged) ----------------
__global__ __launch_bounds__(64) void normalize_k(const float* __restrict__ xs,
                                                  float* __restrict__ xn) {
  const int b = blockIdx.x;
  const int l = threadIdx.x;
  const float* x = xs + ((size_t)b * L_ + l) * DIN_;
  const float x0 = x[0], x1 = x[1], x2 = x[2], x3 = x[3], x4 = x[4], x5 = x[5];
  const float prop = fmaxf(x0, 0.f), tx = fmaxf(x1, 0.f);
  const float sp = prop + tx;

  __shared__ float sh[64];
  __shared__ float med_sh;
  sh[l] = sp;
  __syncthreads();
  int rk = 0;
#pragma unroll 8
  for (int j = 0; j < 64; ++j) {
    const float vj = sh[j];
    rk += (vj < sp) || (vj == sp && j < l);
  }
  if (rk == 31) med_sh = sp;
  __syncthreads();
  const float t_ref = fmaxf(med_sh, 1e-6f);

  float f[5];
  f[0] = prop / t_ref;
  f[1] = tx / t_ref;
  f[2] = x2;
  f[3] = log1pf(fmaxf(x3, 0.f));
  f[4] = log1pf(fmaxf(x4, 0.f) / t_ref);
  const float f5 = log1pf(fmaxf(x5, 0.f));

  float* dst = xn + ((size_t)b * L_ + l) * DIN_;
#pragma unroll
  for (int i = 0; i < 5; ++i) {
    float v = f[i];
    float m = wred_sum(v) * (1.f / 64.f);
    float d = v - m;
    float sd = sqrtf(wred_sum(d * d) * (1.f / 64.f)) + 1e-9f;
    const float lo = m - 3.f * sd, hi = m + 3.f * sd;
    const float cv = fminf(fmaxf(v, lo), hi);
    const float m2 = wred_sum(cv) * (1.f / 64.f);
    const float d2 = cv - m2;
    const float sd2 = sqrtf(wred_sum(d2 * d2) * (1.f / 64.f)) + 1e-9f;
    dst[i] = (cv - m2) / sd2;
  }
  dst[5] = f5;
}

// ---------------- positional encoding table ----------------
__global__ void pe_k(float* __restrict__ pe) {
  const int l = blockIdx.x;
  const int i = threadIdx.x;
  const float div = expf(-9.210340371976184f * (2.0f * i) / 256.0f);
  const float ang = (float)l * div;
  pe[l * T_ + 2 * i]     = sinf(ang);
  pe[l * T_ + 2 * i + 1] = cosf(ang);
}

// ---------------- fp32 -> bf16 cast ----------------
__global__ void cast_k(const float* __restrict__ in, ushort_t* __restrict__ out, int n) {
  const int i = blockIdx.x * 256 + threadIdx.x;
  if (i < n) out[i] = f2bf(in[i]);
}

// link_W2 (L,T,T) -> bf16 transposed per-l: out[l][s][t] = in[l][t][s]
__global__ void w2t_k(const float* __restrict__ in, ushort_t* __restrict__ out) {
  const int idx = blockIdx.x * 256 + threadIdx.x;
  const int l = idx >> 16, r = idx & 65535, s = r >> 8, t = r & 255;
  out[idx] = f2bf(in[(l << 16) | (t << 8) | s]);
}

// ---------------- link MLP stage 1 (fp32 compute, bf16 out) ----------------
__global__ __launch_bounds__(256) void link1_k(const float* __restrict__ xn,
                                               const float* __restrict__ W1,
                                               const float* __restrict__ b1,
                                               ushort_t* __restrict__ h) {
  const size_t bl = blockIdx.x;
  const int l = (int)(bl & (L_ - 1));
  const int t = threadIdx.x;
  const float* x = xn + bl * DIN_;
  float a = b1[l * T_ + t];
#pragma unroll
  for (int d = 0; d < DIN_; ++d)
    a = fmaf(x[d], W1[((size_t)l * DIN_ + d) * T_ + t], a);
  h[bl * T_ + t] = f2bf(fmaxf(a, 0.f));
}

// ---------------- MFMA GEMM: C = A(bf16) @ W(bf16 [n][k])^T + epilogue ------
// tile 128x128, 256 threads (4 waves, each 64x64 via 4x4 frags of 16x16x32)
// LDS fragment-ordered: [blk16][kslot][row16][8] -> all ds_read_b128 lane-linear
// EPI: 0 bias->bf16 | 1 bias->f32 | 2 bias+relu->bf16 | 3 bias+pe -> f32+bf16
template <int EPI>
__global__ __launch_bounds__(256) void mgemm(
    const ushort_t* __restrict__ A, long a_rs, long a_zs,
    const ushort_t* __restrict__ W, long w_zs, int K,
    const float* __restrict__ bias, long b_zs,
    const float* __restrict__ pe2,
    ushort_t* __restrict__ ob, long ob_rs, long ob_zs,
    float* __restrict__ of, long of_rs, long of_zs) {
  __shared__ ushort_t lA[4096], lB[4096];
  const int tid = threadIdx.x;
  const int lane = tid & 63, w = tid >> 6;
  const int wr = w >> 1, wc = w & 1;
  const size_t row0 = (size_t)blockIdx.x * 128;
  const int col0 = blockIdx.y * 128;
  const size_t z = blockIdx.z;
  const ushort_t* Az = A + z * a_zs;
  const ushort_t* Wz = W + z * w_zs + (size_t)col0 * K;

  f32x4 acc[4][4];
#pragma unroll
  for (int mi = 0; mi < 4; ++mi)
#pragma unroll
    for (int ni = 0; ni < 4; ++ni) acc[mi][ni] = (f32x4){0.f, 0.f, 0.f, 0.f};

  for (int kt = 0; kt < K; kt += 32) {
    __syncthreads();
#pragma unroll
    for (int rd = 0; rd < 2; ++rd) {
      const int idx = rd * 256 + tid;
      const int m = idx >> 6, ks = (idx >> 4) & 3, rr = idx & 15;
      gl16(Az + (row0 + m * 16 + rr) * a_rs + kt + ks * 8,
           &lA[(size_t)(rd * 256 + (tid & 192)) * 8]);
    }
#pragma unroll
    for (int rd = 0; rd < 2; ++rd) {
      const int idx = rd * 256 + tid;
      const int nb = idx >> 6, ks = (idx >> 4) & 3, cc = idx & 15;
      gl16(Wz + (size_t)(nb * 16 + cc) * K + kt + ks * 8,
           &lB[(size_t)(rd * 256 + (tid & 192)) * 8]);
    }
    __syncthreads();
    bf16x8 af[4], bfr[4];
#pragma unroll
    for (int mi = 0; mi < 4; ++mi)
      af[mi] = *(const bf16x8*)&lA[((wr * 4 + mi) * 64 + lane) * 8];
#pragma unroll
    for (int ni = 0; ni < 4; ++ni)
      bfr[ni] = *(const bf16x8*)&lB[((wc * 4 + ni) * 64 + lane) * 8];
#pragma unroll
    for (int mi = 0; mi < 4; ++mi)
#pragma unroll
      for (int ni = 0; ni < 4; ++ni)
        acc[mi][ni] = __builtin_amdgcn_mfma_f32_16x16x32_bf16(
            af[mi], bfr[ni], acc[mi][ni], 0, 0, 0);
  }

  const int r_in = (lane >> 4) * 4;
  const int c_in = lane & 15;
#pragma unroll
  for (int ni = 0; ni < 4; ++ni) {
    const int cg = col0 + wc * 64 + ni * 16 + c_in;
    const float bs = bias[z * b_zs + cg];
    float pv = 0.f;
    if constexpr (EPI == 3) pv = pe2[z * 256 + cg];
#pragma unroll
    for (int mi = 0; mi < 4; ++mi) {
#pragma unroll
      for (int rg = 0; rg < 4; ++rg) {
        const size_t rowg = row0 + wr * 64 + mi * 16 + r_in + rg;
        float v = acc[mi][ni][rg] + bs;
        if constexpr (EPI == 2) v = fmaxf(v, 0.f);
        if constexpr (EPI == 3) v += pv;
        if constexpr (EPI == 1) {
          of[z * of_zs + rowg * of_rs + cg] = v;
        } else if constexpr (EPI == 3) {
          of[z * of_zs + rowg * of_rs + cg] = v;
          ob[z * ob_zs + rowg * ob_rs + cg] = f2bf(v);
        } else {
          ob[z * ob_zs + rowg * ob_rs + cg] = f2bf(v);
        }
      }
    }
  }
}

// ---------------- fused residual + LayerNorm (dual f32 + bf16 out) ----------
__global__ __launch_bounds__(256) void lnres_k(const float* __restrict__ zb,
                                               const float* __restrict__ g,
                                               const float* __restrict__ bb,
                                               float* __restrict__ y32,
                                               ushort_t* __restrict__ y16) {
  const size_t row = (size_t)blockIdx.x * 4 + (threadIdx.x >> 6);
  const int lane = threadIdx.x & 63;
  const float4 zv = *(const float4*)(zb + row * 256 + lane * 4);
  const float4 yv = *(const float4*)(y32 + row * 256 + lane * 4);
  const float vx = zv.x + yv.x, vy = zv.y + yv.y, vz = zv.z + yv.z, vw = zv.w + yv.w;
  const float s1 = wred_sum(vx + vy + vz + vw);
  const float s2 = wred_sum(vx * vx + vy * vy + vz * vz + vw * vw);
  const float m = s1 * (1.f / 256.f);
  const float var = s2 * (1.f / 256.f) - m * m;
  const float rs = rsqrtf(var + 1e-5f);
  const float4 gv = *(const float4*)(g + lane * 4);
  const float4 bv = *(const float4*)(bb + lane * 4);
  float4 o;
  o.x = (vx - m) * rs * gv.x + bv.x;
  o.y = (vy - m) * rs * gv.y + bv.y;
  o.z = (vz - m) * rs * gv.z + bv.z;
  o.w = (vw - m) * rs * gv.w + bv.w;
  *(float4*)(y32 + row * 256 + lane * 4) = o;
  const unsigned lo = (unsigned)f2bf(o.x) | ((unsigned)f2bf(o.y) << 16);
  const unsigned hi = (unsigned)f2bf(o.z) | ((unsigned)f2bf(o.w) << 16);
  *(uint2*)(y16 + row * 256 + lane * 4) = make_uint2(lo, hi);
}

// ---------------- fused attention per (b, h), bf16 I/O, fp32 math ----------
__global__ __launch_bounds__(256) void attn_k(const ushort_t* __restrict__ qkv,
                                              ushort_t* __restrict__ o) {
  const int b = blockIdx.x, h = blockIdx.y;
  __shared__ float q[64][36], kk[64][36], vv[64][36];
  __shared__ float p[64][68];
  const int tid = threadIdx.x;
  {
    const int r = tid >> 2, c = tid & 3;
    const size_t base = ((size_t)b * L_ + r) * 768 + h * HD_ + c * 8;
#pragma unroll
    for (int mat = 0; mat < 3; ++mat) {
      const uint4 raw = *(const uint4*)(qkv + base + mat * T_);
      const ushort_t* u = (const ushort_t*)&raw;
      float* dst = (mat == 0 ? &q[r][c * 8] : mat == 1 ? &kk[r][c * 8] : &vv[r][c * 8]);
#pragma unroll
      for (int e = 0; e < 8; ++e) dst[e] = bf2f(u[e]);
    }
  }
  __syncthreads();

  const int j = tid & 63, ig = tid >> 6;
  float kr[32];
#pragma unroll
  for (int cc = 0; cc < 8; ++cc) {
    const float4 k4 = *(const float4*)&kk[j][cc * 4];
    kr[cc * 4 + 0] = k4.x; kr[cc * 4 + 1] = k4.y;
    kr[cc * 4 + 2] = k4.z; kr[cc * 4 + 3] = k4.w;
  }
  float s[16];
#pragma unroll
  for (int ii = 0; ii < 16; ++ii) {
    const int i = ig * 16 + ii;
    float a = 0.f;
#pragma unroll
    for (int cc = 0; cc < 8; ++cc) {
      const float4 q4 = *(const float4*)&q[i][cc * 4];
      a = fmaf(q4.x, kr[cc * 4 + 0], a);
      a = fmaf(q4.y, kr[cc * 4 + 1], a);
      a = fmaf(q4.z, kr[cc * 4 + 2], a);
      a = fmaf(q4.w, kr[cc * 4 + 3], a);
    }
    s[ii] = a * 0.17677669529663687f;
  }
#pragma unroll
  for (int ii = 0; ii < 16; ++ii) {
    const float m = wred_max(s[ii]);
    const float e = expf(s[ii] - m);
    const float sum = wred_sum(e);
    p[ig * 16 + ii][j] = e / sum;
  }
  __syncthreads();

  const int d = tid & 31, rr = tid >> 5;
  float vcol[64];
#pragma unroll
  for (int jj = 0; jj < 64; ++jj) vcol[jj] = vv[jj][d];
#pragma unroll
  for (int pas = 0; pas < 8; ++pas) {
    const int i = pas * 8 + rr;
    float a = 0.f;
#pragma unroll
    for (int cc = 0; cc < 16; ++cc) {
      const float4 p4 = *(const float4*)&p[i][cc * 4];
      a = fmaf(p4.x, vcol[cc * 4 + 0], a);
      a = fmaf(p4.y, vcol[cc * 4 + 1], a);
      a = fmaf(p4.z, vcol[cc * 4 + 2], a);
      a = fmaf(p4.w, vcol[cc * 4 + 3], a);
    }
    o[((size_t)b * L_ + i) * T_ + h * HD_ + d] = f2bf(a);
  }
}

// ---------------- pooling (fp32) ----------------
__global__ __launch_bounds__(256) void pooled_k(const float* __restrict__ y,
                                                float* __restrict__ pooled) {
  const size_t b = blockIdx.x;
  const int t = threadIdx.x;
  const float* p = y + b * (L_ * T_) + t;
  float s = 0.f;
#pragma unroll
  for (int l = 0; l < L_; ++l) s += p[l * T_];
  pooled[b * T_ + t] = s * (1.f / 64.f);
}

// ---------------- fp32 head GEMM (64-row tile, relu) ----------------
__global__ __launch_bounds__(256) void headgemm_k(
    const float* __restrict__ A, const float* __restrict__ Wt,
    const float* __restrict__ bias, float* __restrict__ out) {
  const int tid = threadIdx.x;
  const int tx = tid & 63, ty = tid >> 6;
  const int cfull = tx * 4;
  const size_t b0 = (size_t)blockIdx.x * 64;

  __shared__ float At[256][68];

  float4 acc[16];
#pragma unroll
  for (int r = 0; r < 16; ++r) acc[r] = make_float4(0.f, 0.f, 0.f, 0.f);
  const int r0 = ty * 16;

  {
    const int rr = tid >> 6;
    const int k4 = (tid & 63) * 4;
#pragma unroll
    for (int p = 0; p < 16; ++p) {
      const int r = p * 4 + rr;
      const float4 v = *(const float4*)(A + (b0 + r) * 256 + k4);
      At[k4 + 0][r] = v.x;
      At[k4 + 1][r] = v.y;
      At[k4 + 2][r] = v.z;
      At[k4 + 3][r] = v.w;
    }
  }
  __syncthreads();
  const float* wp = Wt + cfull;
#pragma unroll 2
  for (int k = 0; k < 256; ++k) {
    const float4 w = *(const float4*)wp;
    wp += 256;
    const float4* ar = (const float4*)(&At[k][r0]);
    const float4 a0 = ar[0], a1 = ar[1], a2 = ar[2], a3 = ar[3];
    const float av[16] = {a0.x, a0.y, a0.z, a0.w, a1.x, a1.y, a1.z, a1.w,
                          a2.x, a2.y, a2.z, a2.w, a3.x, a3.y, a3.z, a3.w};
#pragma unroll
    for (int r = 0; r < 16; ++r) {
      acc[r].x = fmaf(av[r], w.x, acc[r].x);
      acc[r].y = fmaf(av[r], w.y, acc[r].y);
      acc[r].z = fmaf(av[r], w.z, acc[r].z);
      acc[r].w = fmaf(av[r], w.w, acc[r].w);
    }
  }
  const float4 bb = *(const float4*)(bias + cfull);
#pragma unroll
  for (int r = 0; r < 16; ++r) {
    const size_t row = b0 + r0 + r;
    float4 o;
    o.x = fmaxf(acc[r].x + bb.x, 0.f);
    o.y = fmaxf(acc[r].y + bb.y, 0.f);
    o.z = fmaxf(acc[r].z + bb.z, 0.f);
    o.w = fmaxf(acc[r].w + bb.w, 0.f);
    *(float4*)(out + row * 256 + cfull) = o;
  }
}

__global__ __launch_bounds__(64) void head2_k(const float* __restrict__ hh,
                                              const float* __restrict__ W2,
                                              const float* __restrict__ b2,
                                              float* __restrict__ out) {
  const size_t b = blockIdx.x;
  const int lane = threadIdx.x;
  const float4 hv = *(const float4*)(hh + b * T_ + lane * 4);
  const float4 wv = *(const float4*)(W2 + lane * 4);
  float s = hv.x * wv.x + hv.y * wv.y + hv.z * wv.z + hv.w * wv.w;
  s = wred_sum(s);
  if (lane == 0) out[b] = s + b2[0];
}

// ---------------- launch ----------------
extern "C" void kernel_launch(void* const* d_in, const int* in_sizes, int n_in,
                              void* d_out, int out_size, void* d_ws, size_t ws_size,
                              hipStream_t stream) {
  const float* link_states = (const float*)d_in[0];
  const float* link_W1 = (const float*)d_in[1];
  const float* link_b1 = (const float*)d_in[2];
  const float* link_W2 = (const float*)d_in[3];
  const float* link_b2 = (const float*)d_in[4];
  const float* Wqkv = (const float*)d_in[5];
  const float* bqkv = (const float*)d_in[6];
  const float* Wo = (const float*)d_in[7];
  const float* bo = (const float*)d_in[8];
  const float* ln1_g = (const float*)d_in[9];
  const float* ln1_b = (const float*)d_in[10];
  const float* Wff1 = (const float*)d_in[11];
  const float* bff1 = (const float*)d_in[12];
  const float* Wff2 = (const float*)d_in[13];
  const float* bff2 = (const float*)d_in[14];
  const float* ln2_g = (const float*)d_in[15];
  const float* ln2_b = (const float*)d_in[16];
  const float* head_W1 = (const float*)d_in[17];
  const float* head_b1 = (const float*)d_in[18];
  const float* head_W2 = (const float*)d_in[19];
  const float* head_b2 = (const float*)d_in[20];

  char* base = (char*)d_ws;
  size_t off = 0;
  auto alloc = [&](size_t bytes) -> char* {
    char* p = base + off;
    off = (off + bytes + 255) & ~(size_t)255;
    return p;
  };

  // ---- fixed region (~29.4 MB) ----
  ushort_t* Wqkv16 = (ushort_t*)alloc((size_t)NL_ * 768 * 256 * 2);
  ushort_t* Wo16   = (ushort_t*)alloc((size_t)NL_ * 256 * 256 * 2);
  ushort_t* Wff116 = (ushort_t*)alloc((size_t)NL_ * 1024 * 256 * 2);
  ushort_t* Wff216 = (ushort_t*)alloc((size_t)NL_ * 256 * 1024 * 2);
  ushort_t* W2T16  = (ushort_t*)alloc((size_t)L_ * 256 * 256 * 2);
  float* pe     = (float*)alloc((size_t)L_ * T_ * 4);
  float* xn     = (float*)alloc((size_t)B_ * L_ * DIN_ * 4);
  float* pooled = (float*)alloc((size_t)B_ * T_ * 4);
  float* hh     = (float*)alloc((size_t)B_ * T_ * 4);

  // ---- chunked region: 327,680 B per batch element ----
  const size_t fixed_end = off;
  const size_t availB = (ws_size > fixed_end + 65536) ? (ws_size - fixed_end - 65536) : 0;
  int NC = 1;
  while (NC < 32 && (size_t)(B_ / NC) * 327680ull > availB) NC <<= 1;
  const int Bc = B_ / NC;  // >= 128

  float*    y32  = (float*)alloc((size_t)Bc * L_ * T_ * 4);
  ushort_t* y16  = (ushort_t*)alloc((size_t)Bc * L_ * T_ * 2);
  ushort_t* bufQ = (ushort_t*)alloc((size_t)Bc * L_ * DFF_ * 2);  // qkv(768)/ff1(1024)
  ushort_t* bufO = (ushort_t*)alloc((size_t)Bc * L_ * T_ * 2);    // h / attn-out
  float*    zbuf = (float*)alloc((size_t)Bc * L_ * T_ * 4);

  // ---- prep ----
  cast_k<<<(NL_ * 768 * 256 + 255) / 256, 256, 0, stream>>>(Wqkv, Wqkv16, NL_ * 768 * 256);
  cast_k<<<(NL_ * 256 * 256 + 255) / 256, 256, 0, stream>>>(Wo, Wo16, NL_ * 256 * 256);
  cast_k<<<(NL_ * 1024 * 256 + 255) / 256, 256, 0, stream>>>(Wff1, Wff116, NL_ * 1024 * 256);
  cast_k<<<(NL_ * 256 * 1024 + 255) / 256, 256, 0, stream>>>(Wff2, Wff216, NL_ * 256 * 1024);
  w2t_k<<<(L_ * 256 * 256) / 256, 256, 0, stream>>>(link_W2, W2T16);
  pe_k<<<L_, 128, 0, stream>>>(pe);
  normalize_k<<<B_, 64, 0, stream>>>(link_states, xn);

  for (int c = 0; c < NC; ++c) {
    const size_t bs = (size_t)c * Bc;
    const int Mt = (Bc * L_) / 128;  // M tiles for main GEMMs

    // ---- link MLP ----
    link1_k<<<Bc * L_, 256, 0, stream>>>(xn + bs * L_ * DIN_, link_W1, link_b1, bufO);
    // y = h @ W2[l] + b2[l] + pe   (z = l, rows = b)
    mgemm<3><<<dim3(Bc / 128, 2, L_), 256, 0, stream>>>(
        bufO, L_ * T_, T_, W2T16, (long)T_ * T_, T_,
        link_b2, T_, pe,
        y16, L_ * T_, T_, y32, L_ * T_, T_);

    for (int l = 0; l < NL_; ++l) {
      // qkv = y @ Wqkv[l]^T + bqkv[l]  -> bf16
      mgemm<0><<<dim3(Mt, 6, 1), 256, 0, stream>>>(
          y16, T_, 0, Wqkv16 + (size_t)l * 768 * 256, 0, T_,
          bqkv + l * 768, 0, nullptr,
          bufQ, 768, 0, nullptr, 0, 0);
      // attention
      attn_k<<<dim3(Bc, H_, 1), 256, 0, stream>>>(bufQ, bufO);
      // zbuf = attn_out @ Wo[l]^T + bo[l]  -> f32
      mgemm<1><<<dim3(Mt, 2, 1), 256, 0, stream>>>(
          bufO, T_, 0, Wo16 + (size_t)l * 256 * 256, 0, T_,
          bo + l * 256, 0, nullptr,
          nullptr, 0, 0, zbuf, T_, 0);
      // y = LN(y + zbuf)
      lnres_k<<<(Bc * L_) / 4, 256, 0, stream>>>(zbuf, ln1_g + l * 256, ln1_b + l * 256,
                                                 y32, y16);
      // ff1 = relu(y @ Wff1[l]^T + bff1[l]) -> bf16
      mgemm<2><<<dim3(Mt, 8, 1), 256, 0, stream>>>(
          y16, T_, 0, Wff116 + (size_t)l * 1024 * 256, 0, T_,
          bff1 + l * 1024, 0, nullptr,
          bufQ, DFF_, 0, nullptr, 0, 0);
      // zbuf = ff1 @ Wff2[l]^T + bff2[l] -> f32   (K = 1024)
      mgemm<1><<<dim3(Mt, 2, 1), 256, 0, stream>>>(
          bufQ, DFF_, 0, Wff216 + (size_t)l * 256 * 1024, 0, DFF_,
          bff2 + l * 256, 0, nullptr,
          nullptr, 0, 0, zbuf, T_, 0);
      // y = LN(y + zbuf)
      lnres_k<<<(Bc * L_) / 4, 256, 0, stream>>>(zbuf, ln2_g + l * 256, ln2_b + l * 256,
                                                 y32, y16);
    }

    pooled_k<<<Bc, 256, 0, stream>>>(y32, pooled + bs * T_);
  }

  // ---- head (fp32) ----
  headgemm_k<<<B_ / 64, 256, 0, stream>>>(pooled, head_W1, head_b1, hh);
  head2_k<<<B_, 64, 0, stream>>>(hh, head_W2, head_b2, (float*)d_out);
}

// Round 4
// 6539.061 us; speedup vs baseline: 4.1516x; 1.2692x over previous
//
#include <hip/hip_runtime.h>
#include <cstddef>

#define B_   4096
#define L_   64
#define T_   256
#define H_   8
#define HD_  32
#define NL_  4
#define DFF_ 1024
#define DIN_ 6

typedef unsigned short ushort_t;
typedef __attribute__((ext_vector_type(8))) short bf16x8;
typedef __attribute__((ext_vector_type(4))) float f32x4;

// ---------------- helpers ----------------
__device__ __forceinline__ float wred_sum(float v) {
#pragma unroll
  for (int off = 32; off >= 1; off >>= 1) v += __shfl_xor(v, off, 64);
  return v;
}
__device__ __forceinline__ ushort_t f2bf(float f) {
  unsigned u = __builtin_bit_cast(unsigned, f);
  u += 0x7fffu + ((u >> 16) & 1u);  // RNE
  return (ushort_t)(u >> 16);
}
__device__ __forceinline__ float bf2f(ushort_t h) {
  unsigned u = ((unsigned)h) << 16;
  return __builtin_bit_cast(float, u);
}
__device__ __forceinline__ void gl16(const ushort_t* g, const ushort_t* l) {
  __builtin_amdgcn_global_load_lds(
      (const __attribute__((address_space(1))) unsigned int*)g,
      (__attribute__((address_space(3))) unsigned int*)l, 16, 0, 0);
}

// ---------------- input normalization (fp32) ----------------
__global__ __launch_bounds__(64) void normalize_k(const float* __restrict__ xs,
                                                  float* __restrict__ xn) {
  const int b = blockIdx.x;
  const int l = threadIdx.x;
  const float* x = xs + ((size_t)b * L_ + l) * DIN_;
  const float x0 = x[0], x1 = x[1], x2 = x[2], x3 = x[3], x4 = x[4], x5 = x[5];
  const float prop = fmaxf(x0, 0.f), tx = fmaxf(x1, 0.f);
  const float sp = prop + tx;

  __shared__ float sh[64];
  __shared__ float med_sh;
  sh[l] = sp;
  __syncthreads();
  int rk = 0;
#pragma unroll 8
  for (int j = 0; j < 64; ++j) {
    const float vj = sh[j];
    rk += (vj < sp) || (vj == sp && j < l);
  }
  if (rk == 31) med_sh = sp;
  __syncthreads();
  const float t_ref = fmaxf(med_sh, 1e-6f);

  float f[5];
  f[0] = prop / t_ref;
  f[1] = tx / t_ref;
  f[2] = x2;
  f[3] = log1pf(fmaxf(x3, 0.f));
  f[4] = log1pf(fmaxf(x4, 0.f) / t_ref);
  const float f5 = log1pf(fmaxf(x5, 0.f));

  float* dst = xn + ((size_t)b * L_ + l) * DIN_;
#pragma unroll
  for (int i = 0; i < 5; ++i) {
    float v = f[i];
    float m = wred_sum(v) * (1.f / 64.f);
    float d = v - m;
    float sd = sqrtf(wred_sum(d * d) * (1.f / 64.f)) + 1e-9f;
    const float lo = m - 3.f * sd, hi = m + 3.f * sd;
    const float cv = fminf(fmaxf(v, lo), hi);
    const float m2 = wred_sum(cv) * (1.f / 64.f);
    const float d2 = cv - m2;
    const float sd2 = sqrtf(wred_sum(d2 * d2) * (1.f / 64.f)) + 1e-9f;
    dst[i] = (cv - m2) / sd2;
  }
  dst[5] = f5;
}

// ---------------- positional encoding table ----------------
__global__ void pe_k(float* __restrict__ pe) {
  const int l = blockIdx.x;
  const int i = threadIdx.x;
  const float div = expf(-9.210340371976184f * (2.0f * i) / 256.0f);
  const float ang = (float)l * div;
  pe[l * T_ + 2 * i]     = sinf(ang);
  pe[l * T_ + 2 * i + 1] = cosf(ang);
}

// ---------------- fp32 -> bf16 cast ----------------
__global__ void cast_k(const float* __restrict__ in, ushort_t* __restrict__ out, int n) {
  const int i = blockIdx.x * 256 + threadIdx.x;
  if (i < n) out[i] = f2bf(in[i]);
}

// link_W2 (L,T,T) -> bf16 transposed per-l: out[l][s][t] = in[l][t][s]
__global__ void w2t_k(const float* __restrict__ in, ushort_t* __restrict__ out) {
  const int idx = blockIdx.x * 256 + threadIdx.x;
  const int l = idx >> 16, r = idx & 65535, s = r >> 8, t = r & 255;
  out[idx] = f2bf(in[(l << 16) | (t << 8) | s]);
}

// ---------------- link MLP stage 1 (fp32 compute, bf16 out) ----------------
__global__ __launch_bounds__(256) void link1_k(const float* __restrict__ xn,
                                               const float* __restrict__ W1,
                                               const float* __restrict__ b1,
                                               ushort_t* __restrict__ h) {
  const size_t bl = blockIdx.x;
  const int l = (int)(bl & (L_ - 1));
  const int t = threadIdx.x;
  const float* x = xn + bl * DIN_;
  float a = b1[l * T_ + t];
#pragma unroll
  for (int d = 0; d < DIN_; ++d)
    a = fmaf(x[d], W1[((size_t)l * DIN_ + d) * T_ + t], a);
  h[bl * T_ + t] = f2bf(fmaxf(a, 0.f));
}

// ---------------- MFMA GEMM 128x128: C = A @ W^T + epilogue ----------------
// EPI: 0 bias->bf16 | 2 bias+relu->bf16 | 3 bias+pe -> f32+bf16
template <int EPI>
__global__ __launch_bounds__(256) void mgemm(
    const ushort_t* __restrict__ A, long a_rs, long a_zs,
    const ushort_t* __restrict__ W, long w_zs, int K,
    const float* __restrict__ bias, long b_zs,
    const float* __restrict__ pe2,
    ushort_t* __restrict__ ob, long ob_rs, long ob_zs,
    float* __restrict__ of, long of_rs, long of_zs) {
  __shared__ ushort_t lA[4096], lB[4096];
  const int tid = threadIdx.x;
  const int lane = tid & 63, w = tid >> 6;
  const int wr = w >> 1, wc = w & 1;
  const size_t row0 = (size_t)blockIdx.x * 128;
  const int col0 = blockIdx.y * 128;
  const size_t z = blockIdx.z;
  const ushort_t* Az = A + z * a_zs;
  const ushort_t* Wz = W + z * w_zs + (size_t)col0 * K;

  f32x4 acc[4][4];
#pragma unroll
  for (int mi = 0; mi < 4; ++mi)
#pragma unroll
    for (int ni = 0; ni < 4; ++ni) acc[mi][ni] = (f32x4){0.f, 0.f, 0.f, 0.f};

  for (int kt = 0; kt < K; kt += 32) {
    __syncthreads();
#pragma unroll
    for (int rd = 0; rd < 2; ++rd) {
      const int idx = rd * 256 + tid;
      const int m = idx >> 6, ks = (idx >> 4) & 3, rr = idx & 15;
      gl16(Az + (row0 + m * 16 + rr) * a_rs + kt + ks * 8,
           &lA[(size_t)(rd * 256 + (tid & 192)) * 8]);
    }
#pragma unroll
    for (int rd = 0; rd < 2; ++rd) {
      const int idx = rd * 256 + tid;
      const int nb = idx >> 6, ks = (idx >> 4) & 3, cc = idx & 15;
      gl16(Wz + (size_t)(nb * 16 + cc) * K + kt + ks * 8,
           &lB[(size_t)(rd * 256 + (tid & 192)) * 8]);
    }
    __syncthreads();
    bf16x8 af[4], bfr[4];
#pragma unroll
    for (int mi = 0; mi < 4; ++mi)
      af[mi] = *(const bf16x8*)&lA[((wr * 4 + mi) * 64 + lane) * 8];
#pragma unroll
    for (int ni = 0; ni < 4; ++ni)
      bfr[ni] = *(const bf16x8*)&lB[((wc * 4 + ni) * 64 + lane) * 8];
#pragma unroll
    for (int mi = 0; mi < 4; ++mi)
#pragma unroll
      for (int ni = 0; ni < 4; ++ni)
        acc[mi][ni] = __builtin_amdgcn_mfma_f32_16x16x32_bf16(
            af[mi], bfr[ni], acc[mi][ni], 0, 0, 0);
  }

  const int r_in = (lane >> 4) * 4;
  const int c_in = lane & 15;
#pragma unroll
  for (int ni = 0; ni < 4; ++ni) {
    const int cg = col0 + wc * 64 + ni * 16 + c_in;
    const float bs = bias[z * b_zs + cg];
    float pv = 0.f;
    if constexpr (EPI == 3) pv = pe2[z * 256 + cg];
#pragma unroll
    for (int mi = 0; mi < 4; ++mi) {
#pragma unroll
      for (int rg = 0; rg < 4; ++rg) {
        const size_t rowg = row0 + wr * 64 + mi * 16 + r_in + rg;
        float v = acc[mi][ni][rg] + bs;
        if constexpr (EPI == 2) v = fmaxf(v, 0.f);
        if constexpr (EPI == 3) {
          v += pv;
          of[z * of_zs + rowg * of_rs + cg] = v;
          ob[z * ob_zs + rowg * ob_rs + cg] = f2bf(v);
        } else {
          ob[z * ob_zs + rowg * ob_rs + cg] = f2bf(v);
        }
      }
    }
  }
}

// ---------------- MFMA GEMM 128x256 + residual + LayerNorm fused ----------
// 512 threads, 8 waves (2 wave-rows x 4 wave-cols); full N=256 row per block
__global__ __launch_bounds__(512) void mgemmln(
    const ushort_t* __restrict__ A, long a_rs,
    const ushort_t* __restrict__ W, int K,
    const float* __restrict__ bias,
    const float* __restrict__ lng, const float* __restrict__ lnb,
    float* __restrict__ y32, ushort_t* __restrict__ y16) {
  __shared__ ushort_t lA[4096];   // 128 x 32 fragment-ordered
  __shared__ ushort_t lB[8192];   // 256 x 32 fragment-ordered
  __shared__ float red[2][4][128];
  const int tid = threadIdx.x;
  const int lane = tid & 63, w = tid >> 6;
  const int wr = w >> 2, wc = w & 3;
  const size_t row0 = (size_t)blockIdx.x * 128;

  f32x4 acc[4][4];
#pragma unroll
  for (int mi = 0; mi < 4; ++mi)
#pragma unroll
    for (int ni = 0; ni < 4; ++ni) acc[mi][ni] = (f32x4){0.f, 0.f, 0.f, 0.f};

  for (int kt = 0; kt < K; kt += 32) {
    __syncthreads();
    {
      const int m = tid >> 6, ks = (tid >> 4) & 3, rr = tid & 15;
      gl16(A + (row0 + m * 16 + rr) * a_rs + kt + ks * 8,
           &lA[(size_t)(tid & ~63) * 8]);
    }
#pragma unroll
    for (int rd = 0; rd < 2; ++rd) {
      const int idx = rd * 512 + tid;
      const int nb = idx >> 6, ks = (idx >> 4) & 3, cc = idx & 15;
      gl16(W + (size_t)(nb * 16 + cc) * K + kt + ks * 8,
           &lB[(size_t)(rd * 512 + (tid & ~63)) * 8]);
    }
    __syncthreads();
    bf16x8 af[4], bfr[4];
#pragma unroll
    for (int mi = 0; mi < 4; ++mi)
      af[mi] = *(const bf16x8*)&lA[((wr * 4 + mi) * 64 + lane) * 8];
#pragma unroll
    for (int ni = 0; ni < 4; ++ni)
      bfr[ni] = *(const bf16x8*)&lB[((wc * 4 + ni) * 64 + lane) * 8];
#pragma unroll
    for (int mi = 0; mi < 4; ++mi)
#pragma unroll
      for (int ni = 0; ni < 4; ++ni)
        acc[mi][ni] = __builtin_amdgcn_mfma_f32_16x16x32_bf16(
            af[mi], bfr[ni], acc[mi][ni], 0, 0, 0);
  }

  const int r_in = (lane >> 4) * 4;
  const int c_in = lane & 15;
  float bcol[4];
#pragma unroll
  for (int ni = 0; ni < 4; ++ni) bcol[ni] = bias[wc * 64 + ni * 16 + c_in];

  // z = acc + bias + residual; per-row partial stats -> LDS
#pragma unroll
  for (int mi = 0; mi < 4; ++mi) {
#pragma unroll
    for (int rg = 0; rg < 4; ++rg) {
      const int row_l = wr * 64 + mi * 16 + r_in + rg;
      const size_t rowg = row0 + row_l;
      float s1 = 0.f, s2 = 0.f;
#pragma unroll
      for (int ni = 0; ni < 4; ++ni) {
        const int cg = wc * 64 + ni * 16 + c_in;
        const float zv = acc[mi][ni][rg] + bcol[ni] + y32[rowg * 256 + cg];
        acc[mi][ni][rg] = zv;
        s1 += zv;
        s2 += zv * zv;
      }
#pragma unroll
      for (int off = 1; off <= 8; off <<= 1) {
        s1 += __shfl_xor(s1, off, 64);
        s2 += __shfl_xor(s2, off, 64);
      }
      if (c_in == 0) {
        red[0][wc][row_l] = s1;
        red[1][wc][row_l] = s2;
      }
    }
  }
  __syncthreads();

#pragma unroll
  for (int mi = 0; mi < 4; ++mi) {
#pragma unroll
    for (int rg = 0; rg < 4; ++rg) {
      const int row_l = wr * 64 + mi * 16 + r_in + rg;
      const size_t rowg = row0 + row_l;
      const float S1 = red[0][0][row_l] + red[0][1][row_l] + red[0][2][row_l] + red[0][3][row_l];
      const float S2 = red[1][0][row_l] + red[1][1][row_l] + red[1][2][row_l] + red[1][3][row_l];
      const float m = S1 * (1.f / 256.f);
      const float var = S2 * (1.f / 256.f) - m * m;
      const float rs = rsqrtf(var + 1e-5f);
#pragma unroll
      for (int ni = 0; ni < 4; ++ni) {
        const int cg = wc * 64 + ni * 16 + c_in;
        const float v = (acc[mi][ni][rg] - m) * rs * lng[cg] + lnb[cg];
        y32[rowg * 256 + cg] = v;
        y16[rowg * 256 + cg] = f2bf(v);
      }
    }
  }
}

// ---------------- MFMA attention: one block per b, 4 waves x 2 heads -------
__global__ __launch_bounds__(256) void attn_m(const ushort_t* __restrict__ qkv,
                                              ushort_t* __restrict__ o) {
  __shared__ ushort_t PT[4][64][72];   // P[q][kk], per wave
  __shared__ ushort_t VT[4][32][72];   // V^T[d][kk], per wave
  const int b = blockIdx.x;
  const int tid = threadIdx.x, lane = tid & 63, w = tid >> 6;
  const int li = lane & 15, g = lane >> 4;
  const size_t qkvb = (size_t)b * 64 * 768;
  const float scale = 0.17677669529663687f;  // 1/sqrt(32)

  for (int hi = 0; hi < 2; ++hi) {
    const int h = w * 2 + hi;
    const int hoff = h * 32;

    // K as A-frags, Q as B-frags (direct from global)
    bf16x8 ka[4], qb[4];
#pragma unroll
    for (int mi = 0; mi < 4; ++mi)
      ka[mi] = *(const bf16x8*)(qkv + qkvb + (size_t)(16 * mi + li) * 768 + 256 + hoff + g * 8);
#pragma unroll
    for (int ni = 0; ni < 4; ++ni)
      qb[ni] = *(const bf16x8*)(qkv + qkvb + (size_t)(16 * ni + li) * 768 + 0 + hoff + g * 8);

    // stage V^T: lane loads V[kk][dc*8..+7], writes VT[dc*8+e][kk]
#pragma unroll
    for (int j = 0; j < 4; ++j) {
      const int t = j * 64 + lane;
      const int kk = t >> 2, dc = t & 3;
      const uint4 raw = *(const uint4*)(qkv + qkvb + (size_t)kk * 768 + 512 + hoff + dc * 8);
      const ushort_t* u = (const ushort_t*)&raw;
#pragma unroll
      for (int e = 0; e < 8; ++e) VT[w][dc * 8 + e][kk] = u[e];
    }

    // S^T = K . Q^T   (S^T[kk][q])
    f32x4 s[4][4];
#pragma unroll
    for (int mi = 0; mi < 4; ++mi)
#pragma unroll
      for (int ni = 0; ni < 4; ++ni)
        s[mi][ni] = __builtin_amdgcn_mfma_f32_16x16x32_bf16(
            ka[mi], qb[ni], (f32x4){0.f, 0.f, 0.f, 0.f}, 0, 0, 0);

    // softmax over kk for each q (= 16*ni + li)
#pragma unroll
    for (int ni = 0; ni < 4; ++ni) {
      float mx = -3.4e38f;
#pragma unroll
      for (int mi = 0; mi < 4; ++mi)
#pragma unroll
        for (int r = 0; r < 4; ++r) {
          s[mi][ni][r] *= scale;
          mx = fmaxf(mx, s[mi][ni][r]);
        }
      mx = fmaxf(mx, __shfl_xor(mx, 16, 64));
      mx = fmaxf(mx, __shfl_xor(mx, 32, 64));
      float sum = 0.f;
#pragma unroll
      for (int mi = 0; mi < 4; ++mi)
#pragma unroll
        for (int r = 0; r < 4; ++r) {
          const float e = expf(s[mi][ni][r] - mx);
          s[mi][ni][r] = e;
          sum += e;
        }
      sum += __shfl_xor(sum, 16, 64);
      sum += __shfl_xor(sum, 32, 64);
      const float inv = 1.f / sum;
      const int q = 16 * ni + li;
#pragma unroll
      for (int mi = 0; mi < 4; ++mi) {
        unsigned lo = (unsigned)f2bf(s[mi][ni][0] * inv) |
                      ((unsigned)f2bf(s[mi][ni][1] * inv) << 16);
        unsigned hi2 = (unsigned)f2bf(s[mi][ni][2] * inv) |
                       ((unsigned)f2bf(s[mi][ni][3] * inv) << 16);
        *(uint2*)&PT[w][q][16 * mi + 4 * g] = make_uint2(lo, hi2);
      }
    }

    // O = P . V  via A=P (from PT), B=V (from VT)
    f32x4 oa[4][2];
#pragma unroll
    for (int mi = 0; mi < 4; ++mi)
#pragma unroll
      for (int n2 = 0; n2 < 2; ++n2) oa[mi][n2] = (f32x4){0.f, 0.f, 0.f, 0.f};
#pragma unroll
    for (int ks = 0; ks < 2; ++ks) {
      bf16x8 pa[4], vb[2];
#pragma unroll
      for (int mi = 0; mi < 4; ++mi)
        pa[mi] = *(const bf16x8*)&PT[w][16 * mi + li][ks * 32 + g * 8];
#pragma unroll
      for (int n2 = 0; n2 < 2; ++n2)
        vb[n2] = *(const bf16x8*)&VT[w][16 * n2 + li][ks * 32 + g * 8];
#pragma unroll
      for (int mi = 0; mi < 4; ++mi)
#pragma unroll
        for (int n2 = 0; n2 < 2; ++n2)
          oa[mi][n2] = __builtin_amdgcn_mfma_f32_16x16x32_bf16(
              pa[mi], vb[n2], oa[mi][n2], 0, 0, 0);
    }

    // write O: row q = 16*mi + 4*g + r, col d = 16*n2 + li
#pragma unroll
    for (int mi = 0; mi < 4; ++mi)
#pragma unroll
      for (int n2 = 0; n2 < 2; ++n2)
#pragma unroll
        for (int r = 0; r < 4; ++r)
          o[(size_t)(b * 64 + 16 * mi + 4 * g + r) * 256 + hoff + 16 * n2 + li] =
              f2bf(oa[mi][n2][r]);
  }
}

// ---------------- pooling (fp32) ----------------
__global__ __launch_bounds__(256) void pooled_k(const float* __restrict__ y,
                                                float* __restrict__ pooled) {
  const size_t b = blockIdx.x;
  const int t = threadIdx.x;
  const float* p = y + b * (L_ * T_) + t;
  float s = 0.f;
#pragma unroll
  for (int l = 0; l < L_; ++l) s += p[l * T_];
  pooled[b * T_ + t] = s * (1.f / 64.f);
}

// ---------------- fp32 head GEMM (64-row tile, relu) ----------------
__global__ __launch_bounds__(256) void headgemm_k(
    const float* __restrict__ A, const float* __restrict__ Wt,
    const float* __restrict__ bias, float* __restrict__ out) {
  const int tid = threadIdx.x;
  const int tx = tid & 63, ty = tid >> 6;
  const int cfull = tx * 4;
  const size_t b0 = (size_t)blockIdx.x * 64;

  __shared__ float At[256][68];

  float4 acc[16];
#pragma unroll
  for (int r = 0; r < 16; ++r) acc[r] = make_float4(0.f, 0.f, 0.f, 0.f);
  const int r0 = ty * 16;

  {
    const int rr = tid >> 6;
    const int k4 = (tid & 63) * 4;
#pragma unroll
    for (int p = 0; p < 16; ++p) {
      const int r = p * 4 + rr;
      const float4 v = *(const float4*)(A + (b0 + r) * 256 + k4);
      At[k4 + 0][r] = v.x;
      At[k4 + 1][r] = v.y;
      At[k4 + 2][r] = v.z;
      At[k4 + 3][r] = v.w;
    }
  }
  __syncthreads();
  const float* wp = Wt + cfull;
#pragma unroll 2
  for (int k = 0; k < 256; ++k) {
    const float4 w = *(const float4*)wp;
    wp += 256;
    const float4* ar = (const float4*)(&At[k][r0]);
    const float4 a0 = ar[0], a1 = ar[1], a2 = ar[2], a3 = ar[3];
    const float av[16] = {a0.x, a0.y, a0.z, a0.w, a1.x, a1.y, a1.z, a1.w,
                          a2.x, a2.y, a2.z, a2.w, a3.x, a3.y, a3.z, a3.w};
#pragma unroll
    for (int r = 0; r < 16; ++r) {
      acc[r].x = fmaf(av[r], w.x, acc[r].x);
      acc[r].y = fmaf(av[r], w.y, acc[r].y);
      acc[r].z = fmaf(av[r], w.z, acc[r].z);
      acc[r].w = fmaf(av[r], w.w, acc[r].w);
    }
  }
  const float4 bb = *(const float4*)(bias + cfull);
#pragma unroll
  for (int r = 0; r < 16; ++r) {
    const size_t row = b0 + r0 + r;
    float4 o;
    o.x = fmaxf(acc[r].x + bb.x, 0.f);
    o.y = fmaxf(acc[r].y + bb.y, 0.f);
    o.z = fmaxf(acc[r].z + bb.z, 0.f);
    o.w = fmaxf(acc[r].w + bb.w, 0.f);
    *(float4*)(out + row * 256 + cfull) = o;
  }
}

__global__ __launch_bounds__(64) void head2_k(const float* __restrict__ hh,
                                              const float* __restrict__ W2,
                                              const float* __restrict__ b2,
                                              float* __restrict__ out) {
  const size_t b = blockIdx.x;
  const int lane = threadIdx.x;
  const float4 hv = *(const float4*)(hh + b * T_ + lane * 4);
  const float4 wv = *(const float4*)(W2 + lane * 4);
  float s = hv.x * wv.x + hv.y * wv.y + hv.z * wv.z + hv.w * wv.w;
  s = wred_sum(s);
  if (lane == 0) out[b] = s + b2[0];
}

// ---------------- launch ----------------
extern "C" void kernel_launch(void* const* d_in, const int* in_sizes, int n_in,
                              void* d_out, int out_size, void* d_ws, size_t ws_size,
                              hipStream_t stream) {
  const float* link_states = (const float*)d_in[0];
  const float* link_W1 = (const float*)d_in[1];
  const float* link_b1 = (const float*)d_in[2];
  const float* link_W2 = (const float*)d_in[3];
  const float* link_b2 = (const float*)d_in[4];
  const float* Wqkv = (const float*)d_in[5];
  const float* bqkv = (const float*)d_in[6];
  const float* Wo = (const float*)d_in[7];
  const float* bo = (const float*)d_in[8];
  const float* ln1_g = (const float*)d_in[9];
  const float* ln1_b = (const float*)d_in[10];
  const float* Wff1 = (const float*)d_in[11];
  const float* bff1 = (const float*)d_in[12];
  const float* Wff2 = (const float*)d_in[13];
  const float* bff2 = (const float*)d_in[14];
  const float* ln2_g = (const float*)d_in[15];
  const float* ln2_b = (const float*)d_in[16];
  const float* head_W1 = (const float*)d_in[17];
  const float* head_b1 = (const float*)d_in[18];
  const float* head_W2 = (const float*)d_in[19];
  const float* head_b2 = (const float*)d_in[20];

  char* base = (char*)d_ws;
  size_t off = 0;
  auto alloc = [&](size_t bytes) -> char* {
    char* p = base + off;
    off = (off + bytes + 255) & ~(size_t)255;
    return p;
  };

  // ---- fixed region (~29.4 MB) ----
  ushort_t* Wqkv16 = (ushort_t*)alloc((size_t)NL_ * 768 * 256 * 2);
  ushort_t* Wo16   = (ushort_t*)alloc((size_t)NL_ * 256 * 256 * 2);
  ushort_t* Wff116 = (ushort_t*)alloc((size_t)NL_ * 1024 * 256 * 2);
  ushort_t* Wff216 = (ushort_t*)alloc((size_t)NL_ * 256 * 1024 * 2);
  ushort_t* W2T16  = (ushort_t*)alloc((size_t)L_ * 256 * 256 * 2);
  float* pe     = (float*)alloc((size_t)L_ * T_ * 4);
  float* xn     = (float*)alloc((size_t)B_ * L_ * DIN_ * 4);
  float* pooled = (float*)alloc((size_t)B_ * T_ * 4);
  float* hh     = (float*)alloc((size_t)B_ * T_ * 4);

  // ---- chunked region: 262,144 B per batch element ----
  const size_t fixed_end = off;
  const size_t availB = (ws_size > fixed_end + 65536) ? (ws_size - fixed_end - 65536) : 0;
  int NC = 1;
  while (NC < 32 && (size_t)(B_ / NC) * 262144ull > availB) NC <<= 1;
  const int Bc = B_ / NC;  // >= 128

  float*    y32  = (float*)alloc((size_t)Bc * L_ * T_ * 4);
  ushort_t* y16  = (ushort_t*)alloc((size_t)Bc * L_ * T_ * 2);
  ushort_t* bufQ = (ushort_t*)alloc((size_t)Bc * L_ * DFF_ * 2);  // qkv(768)/ff1(1024)
  ushort_t* bufO = (ushort_t*)alloc((size_t)Bc * L_ * T_ * 2);    // h / attn-out

  // ---- prep ----
  cast_k<<<(NL_ * 768 * 256 + 255) / 256, 256, 0, stream>>>(Wqkv, Wqkv16, NL_ * 768 * 256);
  cast_k<<<(NL_ * 256 * 256 + 255) / 256, 256, 0, stream>>>(Wo, Wo16, NL_ * 256 * 256);
  cast_k<<<(NL_ * 1024 * 256 + 255) / 256, 256, 0, stream>>>(Wff1, Wff116, NL_ * 1024 * 256);
  cast_k<<<(NL_ * 256 * 1024 + 255) / 256, 256, 0, stream>>>(Wff2, Wff216, NL_ * 256 * 1024);
  w2t_k<<<(L_ * 256 * 256) / 256, 256, 0, stream>>>(link_W2, W2T16);
  pe_k<<<L_, 128, 0, stream>>>(pe);
  normalize_k<<<B_, 64, 0, stream>>>(link_states, xn);

  for (int c = 0; c < NC; ++c) {
    const size_t bs = (size_t)c * Bc;
    const int Mt = (Bc * L_) / 128;

    // ---- link MLP ----
    link1_k<<<Bc * L_, 256, 0, stream>>>(xn + bs * L_ * DIN_, link_W1, link_b1, bufO);
    mgemm<3><<<dim3(Bc / 128, 2, L_), 256, 0, stream>>>(
        bufO, L_ * T_, T_, W2T16, (long)T_ * T_, T_,
        link_b2, T_, pe,
        y16, L_ * T_, T_, y32, L_ * T_, T_);

    for (int l = 0; l < NL_; ++l) {
      // qkv = y @ Wqkv[l]^T + bqkv[l]  -> bf16
      mgemm<0><<<dim3(Mt, 6, 1), 256, 0, stream>>>(
          y16, T_, 0, Wqkv16 + (size_t)l * 768 * 256, 0, T_,
          bqkv + l * 768, 0, nullptr,
          bufQ, 768, 0, nullptr, 0, 0);
      // attention (MFMA)
      attn_m<<<dim3(Bc, 1, 1), 256, 0, stream>>>(bufQ, bufO);
      // y = LN(y + attn_out @ Wo[l]^T + bo[l])  (fused)
      mgemmln<<<dim3(Mt, 1, 1), 512, 0, stream>>>(
          bufO, T_, Wo16 + (size_t)l * 256 * 256, T_,
          bo + l * 256, ln1_g + l * 256, ln1_b + l * 256, y32, y16);
      // ff1 = relu(y @ Wff1[l]^T + bff1[l]) -> bf16
      mgemm<2><<<dim3(Mt, 8, 1), 256, 0, stream>>>(
          y16, T_, 0, Wff116 + (size_t)l * 1024 * 256, 0, T_,
          bff1 + l * 1024, 0, nullptr,
          bufQ, DFF_, 0, nullptr, 0, 0);
      // y = LN(y + ff1 @ Wff2[l]^T + bff2[l])  (fused, K=1024)
      mgemmln<<<dim3(Mt, 1, 1), 512, 0, stream>>>(
          bufQ, DFF_, Wff216 + (size_t)l * 256 * 1024, DFF_,
          bff2 + l * 256, ln2_g + l * 256, ln2_b + l * 256, y32, y16);
    }

    pooled_k<<<Bc, 256, 0, stream>>>(y32, pooled + bs * T_);
  }

  // ---- head (fp32) ----
  headgemm_k<<<B_ / 64, 256, 0, stream>>>(pooled, head_W1, head_b1, hh);
  head2_k<<<B_, 64, 0, stream>>>(hh, head_W2, head_b2, (float*)d_out);
}